// Round 1
// 230.017 us; speedup vs baseline: 1.1104x; 1.1104x over previous
//
#include <hip/hip_runtime.h>
#include <math.h>

#define NSITE 100
#define NOCC  50
#define DIM   128
#define KDET  4
#define NTAB  400                         // K*(N_UP+N_DOWN)
#define TP_FLOATS ((4 + 144) * NTAB)      // T then P' in ws

// ---------------------------------------------------------------------------
// R18 collapsed the GEMM into T[4][400]/P'[144][400] table adds.
// R19 (this round): det_kernel is VALU-bound (VALUBusy 89%, MfmaUtil 0).
//  (1) software-pipeline the pivot: col J+1 is updated FIRST, its DPP
//      max-chain + reciprocal then overlap the remaining 2*(48-J) update
//      instructions instead of serializing every step.
//  (2) precise 1/piv (~10 instr, ~50 serial cyc) -> v_rcp_f32 + 1 Newton.
//  (3) permutation parity moved entirely to SALU (chosen-mask popcount);
//      kills perm[] LDS, the 50-iter inversion loop, and one barrier.
//  (4) occupied-index build: serial tid==0 scan (150 LDS-latency iters)
//      -> wave-parallel ballot + prefix-popcount ranks.
// ---------------------------------------------------------------------------

// Wave64 max-reduction via DPP (VALU-only). Lane 63 ends with global max.
__device__ __forceinline__ unsigned dpp_max64_to_lane63(unsigned x) {
  unsigned t;
  t = (unsigned)__builtin_amdgcn_update_dpp((int)x, (int)x, 0x111, 0xf, 0xf, false);
  x = x > t ? x : t;
  t = (unsigned)__builtin_amdgcn_update_dpp((int)x, (int)x, 0x112, 0xf, 0xf, false);
  x = x > t ? x : t;
  t = (unsigned)__builtin_amdgcn_update_dpp((int)x, (int)x, 0x114, 0xf, 0xf, false);
  x = x > t ? x : t;
  t = (unsigned)__builtin_amdgcn_update_dpp((int)x, (int)x, 0x118, 0xf, 0xf, false);
  x = x > t ? x : t;
  t = (unsigned)__builtin_amdgcn_update_dpp((int)x, (int)x, 0x142, 0xa, 0xf, false);
  x = x > t ? x : t;
  t = (unsigned)__builtin_amdgcn_update_dpp((int)x, (int)x, 0x143, 0xc, 0xf, false);
  x = x > t ? x : t;
  return x;
}

#define REPB(X) X(0) X(1) X(2) X(3) X(4) X(5) X(6) X(7) X(8) X(9) \
  X(10) X(11) X(12) X(13) X(14) X(15) X(16) X(17) X(18) X(19) \
  X(20) X(21) X(22) X(23) X(24) X(25) X(26) X(27) X(28) X(29) \
  X(30) X(31) X(32) X(33) X(34) X(35) X(36) X(37) X(38) X(39) \
  X(40) X(41) X(42) X(43) X(44) X(45) X(46) X(47) X(48) X(49)

// step pairs (J, J+1) for the pipelined LU
#define LUPAIR(X) \
  X(0,1) X(1,2) X(2,3) X(3,4) X(4,5) X(5,6) X(6,7) X(7,8) X(8,9) X(9,10) \
  X(10,11) X(11,12) X(12,13) X(13,14) X(14,15) X(15,16) X(16,17) X(17,18) \
  X(18,19) X(19,20) X(20,21) X(21,22) X(22,23) X(23,24) X(24,25) X(25,26) \
  X(26,27) X(27,28) X(28,29) X(29,30) X(30,31) X(31,32) X(32,33) X(33,34) \
  X(34,35) X(35,36) X(36,37) X(37,38) X(38,39) X(39,40) X(40,41) X(41,42) \
  X(42,43) X(43,44) X(44,45) X(45,46) X(46,47) X(47,48) X(48,49)

// ---- Precompute: T[c][j] = tok[c].W_j ; P'[s][j] = pos[s].W_j + b_j ------
__global__ __launch_bounds__(256) void tp_kernel(
    const float* __restrict__ tok, const float* __restrict__ pos,
    const float* __restrict__ W,   const float* __restrict__ bvec,
    float* __restrict__ T, float* __restrict__ P)
{
  const int gid = blockIdx.x * 256 + threadIdx.x;
  if (gid >= 148 * NTAB) return;
  const int row = gid / NTAB;
  const int col = gid - row * NTAB;
  const float4* h4 = (const float4*)((row < 4) ? (tok + (size_t)row * DIM)
                                               : (pos + (size_t)(row - 4) * DIM));
  const float4* w4 = (const float4*)(W + (size_t)col * DIM);
  float acc = 0.0f;
  #pragma unroll
  for (int i = 0; i < DIM / 4; ++i) {
    float4 a = h4[i], b = w4[i];
    acc = fmaf(a.x, b.x, acc);
    acc = fmaf(a.y, b.y, acc);
    acc = fmaf(a.z, b.z, acc);
    acc = fmaf(a.w, b.w, acc);
  }
  if (row < 4) T[(size_t)row * NTAB + col] = acc;
  else         P[(size_t)(row - 4) * NTAB + col] = acc + bvec[col];
}

// One block per (batch, spin). Wave w handles determinant k=w.
// Lane r owns row r of phi in 50 named fp32 registers (r < 50).
__global__ __launch_bounds__(256)
__attribute__((amdgpu_waves_per_eu(7)))
void det_kernel(
    const int*   __restrict__ configs,   // (B,100) int32
    const float* __restrict__ T,         // (4,400)
    const float* __restrict__ P,         // (144,400)  includes bias
    double*      __restrict__ dets)      // (B,2,4,2)  {logdet, sign}
{
  const int b    = blockIdx.x;
  const int spin = blockIdx.y;

  __shared__ int cfg[NSITE];
  __shared__ int idx[NOCC];
  __shared__ unsigned long long omask[2];

  const int tid = threadIdx.x;

  // ---- wave-parallel occupied-index build (ballot + prefix popcount) ----
  // semantics == reference argsort(-mask)[:50] then sort: all occupied
  // sites ascending (capped 50) + smallest unoccupied fills, merged sorted.
  bool occv = false;
  if (tid < NSITE) {
    const int c = configs[(size_t)b * NSITE + tid];
    cfg[tid] = c;
    occv = (spin == 0) ? (c == 1 || c == 3) : (c == 2 || c == 3);
  }
  const unsigned long long bal = __ballot(occv);   // sites 0-63 in wave0, 64-99 in wave1
  if ((tid & 63) == 0 && tid < 128) omask[tid >> 6] = bal;
  __syncthreads();
  if (tid < NSITE) {
    const unsigned long long m0 = omask[0], m1 = omask[1];
    const int mtot = __popcll(m0) + __popcll(m1);
    const int need = (mtot < NOCC) ? (NOCC - mtot) : 0;   // fills required
    int pocc;                                             // #occ sites < tid
    if (tid >= 64) pocc = __popcll(m0) + __popcll(m1 & ((1ull << (tid - 64)) - 1ull));
    else           pocc = __popcll(m0 & ((1ull << tid) - 1ull));
    const int punocc = tid - pocc;                        // #unocc sites < tid
    const bool sel = occv ? (pocc < NOCC) : (punocc < need);
    const int  poscap = (pocc  < NOCC) ? pocc  : NOCC;
    const int  pfill  = (punocc < need) ? punocc : need;
    if (sel) idx[poscap + pfill] = tid;                   // rank among selected
  }
  __syncthreads();

  const int lane = tid & 63;
  const int wave = tid >> 6;
  const int wave_u  = __builtin_amdgcn_readfirstlane(wave);
  const int colbase = spin * 200 + wave_u * 50;          // uniform

  const bool act  = (lane < NOCC);
  const int  site = idx[act ? lane : 0];
  const int  cc0  = cfg[site];
  // colbase is a multiple of 50 -> byte offset multiple of 200 -> 8-aligned
  // (NOT 16): use float2 loads.
  const float2* T2 = (const float2*)(T + (size_t)cc0  * NTAB + colbase);
  const float2* P2 = (const float2*)(P + (size_t)site * NTAB + colbase);

  // ---- assemble phi row: q_j = T[c][cb+j] + P'[site][cb+j] ----
  #define DECLQ(i) float q##i;
  REPB(DECLQ)
  #undef DECLQ
  // groups of 12 + sched_barrier(0) to bound in-flight loads (keep peak
  // register demand under the waves_per_eu(7) budget of 72)
  #define LQ(i0, i1) { float2 a = T2[(i0) / 2], c = P2[(i0) / 2]; \
      q##i0 = a.x + c.x; q##i1 = a.y + c.y; }
  LQ(0, 1)  LQ(2, 3)  LQ(4, 5)  LQ(6, 7)  LQ(8, 9)  LQ(10, 11)
  __builtin_amdgcn_sched_barrier(0);
  LQ(12, 13) LQ(14, 15) LQ(16, 17) LQ(18, 19) LQ(20, 21) LQ(22, 23)
  __builtin_amdgcn_sched_barrier(0);
  LQ(24, 25) LQ(26, 27) LQ(28, 29) LQ(30, 31) LQ(32, 33) LQ(34, 35)
  __builtin_amdgcn_sched_barrier(0);
  LQ(36, 37) LQ(38, 39) LQ(40, 41) LQ(42, 43) LQ(44, 45) LQ(46, 47)
  __builtin_amdgcn_sched_barrier(0);
  LQ(48, 49)
  #undef LQ

  // zero inactive lanes so they never win the pivot and updates stay benign
  #define ZEROQ(i) q##i = act ? q##i : 0.0f;
  REPB(ZEROQ)
  #undef ZEROQ

  // ---- LU (fp32, in place on q), software-pipelined implicit pivoting ----
  // aliveq: per-lane all-ones/zero mask (VGPR). Uniform bookkeeping (esum,
  // sign, parity) lives in SGPRs: p/piv come from readlane -> uniform.
  unsigned aliveq = act ? 0xFFFFFFFFu : 0u;
  float    mant_prod = 1.0f;           // product of pivot mantissas, < 2^50
  int      esum = 0;
  unsigned sgnx = 0u;                  // XOR of pivot sign bits
  unsigned long long chosen = 0ull;    // lanes already used as pivots
  int      invsum = 0;                 // permutation inversions
  const unsigned lu = (unsigned)lane;

  unsigned keyv;
  int   p;    // current pivot lane (uniform)
  float rp;   // reciprocal of current pivot (uniform value)

  // PIVFIN: consume keyv -> p, piv, rp; do SALU accounting; retire lane p.
  #define PIVFIN(Jx) { \
    p = __builtin_amdgcn_readlane((int)keyv, 63) & 63; \
    const float piv = __int_as_float( \
        __builtin_amdgcn_readlane(__float_as_int(q##Jx), p)); \
    const unsigned pb = __float_as_uint(piv); \
    esum += (int)((pb >> 23) & 0xFFu) - 127; \
    sgnx ^= (pb & 0x80000000u); \
    mant_prod *= __uint_as_float((pb & 0x007FFFFFu) | 0x3F800000u); \
    invsum += __popcll(chosen >> (p + 1)); \
    chosen |= 1ull << (unsigned)p; \
    aliveq = ((unsigned)lane == (unsigned)p) ? 0u : aliveq; \
    float r0 = __builtin_amdgcn_rcpf(piv); \
    r0 = fmaf(fmaf(-piv, r0, 1.0f), r0, r0); \
    rp = ((pb & 0x7FFFFFFFu) != 0u) ? r0 : 0.0f; }

  // trailing-column update (cols > J+1); pivot-row element via readlane->SGPR
  #define UPDC(CC) if ((CC) > cJ1) { \
      const float pc = __int_as_float( \
          __builtin_amdgcn_readlane(__float_as_int(q##CC), p)); \
      q##CC = fmaf(-mult, pc, q##CC); }

  // One pipelined step: eliminate with (p,rp) of column J; update col J+1
  // FIRST, launch its pivot key-chain, then the bulk updates hide the DPP
  // chain + rcp latency; PIVFIN lands p/rp for the next step.
  #define LUS(J, J1) { \
    const float mult = __uint_as_float(__float_as_uint(q##J * rp) & aliveq); \
    { const float pc0 = __int_as_float( \
          __builtin_amdgcn_readlane(__float_as_int(q##J1), p)); \
      q##J1 = fmaf(-mult, pc0, q##J1); } \
    keyv = ((__float_as_uint(q##J1) & 0x7FFFFFC0u) | lu) & aliveq; \
    keyv = dpp_max64_to_lane63(keyv); \
    const int cJ1 = (J1); \
    REPB(UPDC) \
    PIVFIN(J1) \
  }

  // prologue: pivot of column 0
  keyv = ((__float_as_uint(q0) & 0x7FFFFFC0u) | lu) & aliveq;
  keyv = dpp_max64_to_lane63(keyv);
  PIVFIN(0)
  // 49 pipelined steps; PIVFIN(49) inside LUS(48,49) closes the accounting
  LUPAIR(LUS)
  #undef LUS
  #undef UPDC
  #undef PIVFIN

  const double logdet =
      log((double)mant_prod) + (double)esum * 0.6931471805599453;
  const int sgn = (((sgnx >> 31) + (unsigned)invsum) & 1u) ? -1 : 1;

  if (lane == 0) {
    size_t o = (((size_t)b * 2 + spin) * KDET + wave) * 2;
    dets[o]     = logdet;
    dets[o + 1] = (double)sgn;
  }
}

// PLANAR complex64 output: out[0..B) = log_abs (real), out[B..2B) = phase (imag)
__global__ __launch_bounds__(256) void combine_kernel(
    const double* __restrict__ dets, float* __restrict__ out, int B)
{
  int b = blockIdx.x * blockDim.x + threadIdx.x;
  if (b >= B) return;
  const double* du = dets + ((size_t)b * 2 + 0) * KDET * 2;
  const double* dd = dets + ((size_t)b * 2 + 1) * KDET * 2;
  double t[KDET], s[KDET], m = -1e300;
  #pragma unroll
  for (int k = 0; k < KDET; ++k) {
    t[k] = du[2 * k] + dd[2 * k];
    s[k] = du[2 * k + 1] * dd[2 * k + 1];
    if (t[k] > m) m = t[k];
  }
  double sum = 0.0;
  #pragma unroll
  for (int k = 0; k < KDET; ++k) {
    if (t[k] > -1e290) sum += s[k] * exp(t[k] - m);
  }
  double p  = (m > -1e290) ? exp(m) * fabs(sum) : 0.0;
  double la = log(p + 1e-30);                    // reproduce ref clamp exactly
  float phase = (sum >= 0.0) ? 0.0f : 3.14159265358979f;
  out[b]     = (float)la;
  out[B + b] = phase;
}

extern "C" void kernel_launch(void* const* d_in, const int* in_sizes, int n_in,
                              void* d_out, int out_size, void* d_ws, size_t ws_size,
                              hipStream_t stream) {
  const int*   configs = (const int*)  d_in[0];
  const float* tok     = (const float*)d_in[1];
  const float* pos     = (const float*)d_in[2];
  const float* W       = (const float*)d_in[3];
  const float* bv      = (const float*)d_in[4];

  float*  wsf  = (float*)d_ws;
  float*  T    = wsf;                       // 4*400 floats
  float*  P    = wsf + 4 * NTAB;            // 144*400 floats
  double* dets = (double*)(wsf + TP_FLOATS);  // 236800B offset, 8-aligned
  const int B = in_sizes[0] / NSITE;        // total ws: ~499KB

  tp_kernel<<<(148 * NTAB + 255) / 256, 256, 0, stream>>>(tok, pos, W, bv, T, P);
  dim3 grid(B, 2);
  det_kernel<<<grid, 256, 0, stream>>>(configs, T, P, dets);
  combine_kernel<<<(B + 255) / 256, 256, 0, stream>>>(dets, (float*)d_out, B);
}

// Round 2
// 226.403 us; speedup vs baseline: 1.1281x; 1.0160x over previous
//
#include <hip/hip_runtime.h>
#include <math.h>

#define NSITE 100
#define NOCC  50
#define DIM   128
#define KDET  4
#define NTAB  400                         // K*(N_UP+N_DOWN)
#define TP_FLOATS ((4 + 144) * NTAB)      // T then P' in ws

// ---------------------------------------------------------------------------
// R18 collapsed the GEMM into T[4][400]/P'[144][400] table adds.
// R19 pipelined the pivot chain + SALU parity: 197 -> 170us, but left
// VGPR_Count=36 -- the 50 live q registers CANNOT fit in 36 arch VGPRs, so
// the compiler was shuffling through AGPRs / scratch (WRITE_SIZE 13.5MB vs
// 0.5MB of real output = spill traffic). Every shuffled q access is +1-2
// VALU ops on the hot path.
// R20 (this round): waves_per_eu 7 -> 6 (budget 72 -> 85) so q0..q49 +
// pipeline transients are fully arch-VGPR-resident. Measured occupancy was
// only 5.2 waves/SIMD anyway, so the cap change costs nothing real.
// ---------------------------------------------------------------------------

// Wave64 max-reduction via DPP (VALU-only). Lane 63 ends with global max.
__device__ __forceinline__ unsigned dpp_max64_to_lane63(unsigned x) {
  unsigned t;
  t = (unsigned)__builtin_amdgcn_update_dpp((int)x, (int)x, 0x111, 0xf, 0xf, false);
  x = x > t ? x : t;
  t = (unsigned)__builtin_amdgcn_update_dpp((int)x, (int)x, 0x112, 0xf, 0xf, false);
  x = x > t ? x : t;
  t = (unsigned)__builtin_amdgcn_update_dpp((int)x, (int)x, 0x114, 0xf, 0xf, false);
  x = x > t ? x : t;
  t = (unsigned)__builtin_amdgcn_update_dpp((int)x, (int)x, 0x118, 0xf, 0xf, false);
  x = x > t ? x : t;
  t = (unsigned)__builtin_amdgcn_update_dpp((int)x, (int)x, 0x142, 0xa, 0xf, false);
  x = x > t ? x : t;
  t = (unsigned)__builtin_amdgcn_update_dpp((int)x, (int)x, 0x143, 0xc, 0xf, false);
  x = x > t ? x : t;
  return x;
}

#define REPB(X) X(0) X(1) X(2) X(3) X(4) X(5) X(6) X(7) X(8) X(9) \
  X(10) X(11) X(12) X(13) X(14) X(15) X(16) X(17) X(18) X(19) \
  X(20) X(21) X(22) X(23) X(24) X(25) X(26) X(27) X(28) X(29) \
  X(30) X(31) X(32) X(33) X(34) X(35) X(36) X(37) X(38) X(39) \
  X(40) X(41) X(42) X(43) X(44) X(45) X(46) X(47) X(48) X(49)

// step pairs (J, J+1) for the pipelined LU
#define LUPAIR(X) \
  X(0,1) X(1,2) X(2,3) X(3,4) X(4,5) X(5,6) X(6,7) X(7,8) X(8,9) X(9,10) \
  X(10,11) X(11,12) X(12,13) X(13,14) X(14,15) X(15,16) X(16,17) X(17,18) \
  X(18,19) X(19,20) X(20,21) X(21,22) X(22,23) X(23,24) X(24,25) X(25,26) \
  X(26,27) X(27,28) X(28,29) X(29,30) X(30,31) X(31,32) X(32,33) X(33,34) \
  X(34,35) X(35,36) X(36,37) X(37,38) X(38,39) X(39,40) X(40,41) X(41,42) \
  X(42,43) X(43,44) X(44,45) X(45,46) X(46,47) X(47,48) X(48,49)

// ---- Precompute: T[c][j] = tok[c].W_j ; P'[s][j] = pos[s].W_j + b_j ------
__global__ __launch_bounds__(256) void tp_kernel(
    const float* __restrict__ tok, const float* __restrict__ pos,
    const float* __restrict__ W,   const float* __restrict__ bvec,
    float* __restrict__ T, float* __restrict__ P)
{
  const int gid = blockIdx.x * 256 + threadIdx.x;
  if (gid >= 148 * NTAB) return;
  const int row = gid / NTAB;
  const int col = gid - row * NTAB;
  const float4* h4 = (const float4*)((row < 4) ? (tok + (size_t)row * DIM)
                                               : (pos + (size_t)(row - 4) * DIM));
  const float4* w4 = (const float4*)(W + (size_t)col * DIM);
  float acc = 0.0f;
  #pragma unroll
  for (int i = 0; i < DIM / 4; ++i) {
    float4 a = h4[i], b = w4[i];
    acc = fmaf(a.x, b.x, acc);
    acc = fmaf(a.y, b.y, acc);
    acc = fmaf(a.z, b.z, acc);
    acc = fmaf(a.w, b.w, acc);
  }
  if (row < 4) T[(size_t)row * NTAB + col] = acc;
  else         P[(size_t)(row - 4) * NTAB + col] = acc + bvec[col];
}

// One block per (batch, spin). Wave w handles determinant k=w.
// Lane r owns row r of phi in 50 named fp32 registers (r < 50).
__global__ __launch_bounds__(256)
__attribute__((amdgpu_waves_per_eu(6)))
void det_kernel(
    const int*   __restrict__ configs,   // (B,100) int32
    const float* __restrict__ T,         // (4,400)
    const float* __restrict__ P,         // (144,400)  includes bias
    double*      __restrict__ dets)      // (B,2,4,2)  {logdet, sign}
{
  const int b    = blockIdx.x;
  const int spin = blockIdx.y;

  __shared__ int cfg[NSITE];
  __shared__ int idx[NOCC];
  __shared__ unsigned long long omask[2];

  const int tid = threadIdx.x;

  // ---- wave-parallel occupied-index build (ballot + prefix popcount) ----
  // semantics == reference argsort(-mask)[:50] then sort: all occupied
  // sites ascending (capped 50) + smallest unoccupied fills, merged sorted.
  bool occv = false;
  if (tid < NSITE) {
    const int c = configs[(size_t)b * NSITE + tid];
    cfg[tid] = c;
    occv = (spin == 0) ? (c == 1 || c == 3) : (c == 2 || c == 3);
  }
  const unsigned long long bal = __ballot(occv);   // sites 0-63 in wave0, 64-99 in wave1
  if ((tid & 63) == 0 && tid < 128) omask[tid >> 6] = bal;
  __syncthreads();
  if (tid < NSITE) {
    const unsigned long long m0 = omask[0], m1 = omask[1];
    const int mtot = __popcll(m0) + __popcll(m1);
    const int need = (mtot < NOCC) ? (NOCC - mtot) : 0;   // fills required
    int pocc;                                             // #occ sites < tid
    if (tid >= 64) pocc = __popcll(m0) + __popcll(m1 & ((1ull << (tid - 64)) - 1ull));
    else           pocc = __popcll(m0 & ((1ull << tid) - 1ull));
    const int punocc = tid - pocc;                        // #unocc sites < tid
    const bool sel = occv ? (pocc < NOCC) : (punocc < need);
    const int  poscap = (pocc  < NOCC) ? pocc  : NOCC;
    const int  pfill  = (punocc < need) ? punocc : need;
    if (sel) idx[poscap + pfill] = tid;                   // rank among selected
  }
  __syncthreads();

  const int lane = tid & 63;
  const int wave = tid >> 6;
  const int wave_u  = __builtin_amdgcn_readfirstlane(wave);
  const int colbase = spin * 200 + wave_u * 50;          // uniform

  const bool act  = (lane < NOCC);
  const int  site = idx[act ? lane : 0];
  const int  cc0  = cfg[site];
  // colbase is a multiple of 50 -> byte offset multiple of 200 -> 8-aligned
  // (NOT 16): use float2 loads.
  const float2* T2 = (const float2*)(T + (size_t)cc0  * NTAB + colbase);
  const float2* P2 = (const float2*)(P + (size_t)site * NTAB + colbase);

  // ---- assemble phi row: q_j = T[c][cb+j] + P'[site][cb+j] ----
  #define DECLQ(i) float q##i;
  REPB(DECLQ)
  #undef DECLQ
  // groups of 12 + sched_barrier(0) to bound in-flight loads (keep peak
  // register demand inside the waves_per_eu(6) budget of 85)
  #define LQ(i0, i1) { float2 a = T2[(i0) / 2], c = P2[(i0) / 2]; \
      q##i0 = a.x + c.x; q##i1 = a.y + c.y; }
  LQ(0, 1)  LQ(2, 3)  LQ(4, 5)  LQ(6, 7)  LQ(8, 9)  LQ(10, 11)
  __builtin_amdgcn_sched_barrier(0);
  LQ(12, 13) LQ(14, 15) LQ(16, 17) LQ(18, 19) LQ(20, 21) LQ(22, 23)
  __builtin_amdgcn_sched_barrier(0);
  LQ(24, 25) LQ(26, 27) LQ(28, 29) LQ(30, 31) LQ(32, 33) LQ(34, 35)
  __builtin_amdgcn_sched_barrier(0);
  LQ(36, 37) LQ(38, 39) LQ(40, 41) LQ(42, 43) LQ(44, 45) LQ(46, 47)
  __builtin_amdgcn_sched_barrier(0);
  LQ(48, 49)
  #undef LQ

  // zero inactive lanes so they never win the pivot and updates stay benign
  #define ZEROQ(i) q##i = act ? q##i : 0.0f;
  REPB(ZEROQ)
  #undef ZEROQ

  // fence: don't let the scheduler blend LU transients into the load phase
  __builtin_amdgcn_sched_barrier(0);

  // ---- LU (fp32, in place on q), software-pipelined implicit pivoting ----
  // aliveq: per-lane all-ones/zero mask (VGPR). Uniform bookkeeping (esum,
  // sign, parity) lives in SGPRs: p/piv come from readlane -> uniform.
  unsigned aliveq = act ? 0xFFFFFFFFu : 0u;
  float    mant_prod = 1.0f;           // product of pivot mantissas, < 2^50
  int      esum = 0;
  unsigned sgnx = 0u;                  // XOR of pivot sign bits
  unsigned long long chosen = 0ull;    // lanes already used as pivots
  int      invsum = 0;                 // permutation inversions
  const unsigned lu = (unsigned)lane;

  unsigned keyv;
  int   p;    // current pivot lane (uniform)
  float rp;   // reciprocal of current pivot (uniform value)

  // PIVFIN: consume keyv -> p, piv, rp; do SALU accounting; retire lane p.
  #define PIVFIN(Jx) { \
    p = __builtin_amdgcn_readlane((int)keyv, 63) & 63; \
    const float piv = __int_as_float( \
        __builtin_amdgcn_readlane(__float_as_int(q##Jx), p)); \
    const unsigned pb = __float_as_uint(piv); \
    esum += (int)((pb >> 23) & 0xFFu) - 127; \
    sgnx ^= (pb & 0x80000000u); \
    mant_prod *= __uint_as_float((pb & 0x007FFFFFu) | 0x3F800000u); \
    invsum += __popcll(chosen >> (p + 1)); \
    chosen |= 1ull << (unsigned)p; \
    aliveq = ((unsigned)lane == (unsigned)p) ? 0u : aliveq; \
    float r0 = __builtin_amdgcn_rcpf(piv); \
    r0 = fmaf(fmaf(-piv, r0, 1.0f), r0, r0); \
    rp = ((pb & 0x7FFFFFFFu) != 0u) ? r0 : 0.0f; }

  // trailing-column update (cols > J+1); pivot-row element via readlane->SGPR
  #define UPDC(CC) if ((CC) > cJ1) { \
      const float pc = __int_as_float( \
          __builtin_amdgcn_readlane(__float_as_int(q##CC), p)); \
      q##CC = fmaf(-mult, pc, q##CC); }

  // One pipelined step: eliminate with (p,rp) of column J; update col J+1
  // FIRST, launch its pivot key-chain, then the bulk updates hide the DPP
  // chain + rcp latency; PIVFIN lands p/rp for the next step.
  #define LUS(J, J1) { \
    const float mult = __uint_as_float(__float_as_uint(q##J * rp) & aliveq); \
    { const float pc0 = __int_as_float( \
          __builtin_amdgcn_readlane(__float_as_int(q##J1), p)); \
      q##J1 = fmaf(-mult, pc0, q##J1); } \
    keyv = ((__float_as_uint(q##J1) & 0x7FFFFFC0u) | lu) & aliveq; \
    keyv = dpp_max64_to_lane63(keyv); \
    const int cJ1 = (J1); \
    REPB(UPDC) \
    PIVFIN(J1) \
  }

  // prologue: pivot of column 0
  keyv = ((__float_as_uint(q0) & 0x7FFFFFC0u) | lu) & aliveq;
  keyv = dpp_max64_to_lane63(keyv);
  PIVFIN(0)
  // 49 pipelined steps; PIVFIN(49) inside LUS(48,49) closes the accounting
  LUPAIR(LUS)
  #undef LUS
  #undef UPDC
  #undef PIVFIN

  const double logdet =
      log((double)mant_prod) + (double)esum * 0.6931471805599453;
  const int sgn = (((sgnx >> 31) + (unsigned)invsum) & 1u) ? -1 : 1;

  if (lane == 0) {
    size_t o = (((size_t)b * 2 + spin) * KDET + wave) * 2;
    dets[o]     = logdet;
    dets[o + 1] = (double)sgn;
  }
}

// PLANAR complex64 output: out[0..B) = log_abs (real), out[B..2B) = phase (imag)
__global__ __launch_bounds__(256) void combine_kernel(
    const double* __restrict__ dets, float* __restrict__ out, int B)
{
  int b = blockIdx.x * blockDim.x + threadIdx.x;
  if (b >= B) return;
  const double* du = dets + ((size_t)b * 2 + 0) * KDET * 2;
  const double* dd = dets + ((size_t)b * 2 + 1) * KDET * 2;
  double t[KDET], s[KDET], m = -1e300;
  #pragma unroll
  for (int k = 0; k < KDET; ++k) {
    t[k] = du[2 * k] + dd[2 * k];
    s[k] = du[2 * k + 1] * dd[2 * k + 1];
    if (t[k] > m) m = t[k];
  }
  double sum = 0.0;
  #pragma unroll
  for (int k = 0; k < KDET; ++k) {
    if (t[k] > -1e290) sum += s[k] * exp(t[k] - m);
  }
  double p  = (m > -1e290) ? exp(m) * fabs(sum) : 0.0;
  double la = log(p + 1e-30);                    // reproduce ref clamp exactly
  float phase = (sum >= 0.0) ? 0.0f : 3.14159265358979f;
  out[b]     = (float)la;
  out[B + b] = phase;
}

extern "C" void kernel_launch(void* const* d_in, const int* in_sizes, int n_in,
                              void* d_out, int out_size, void* d_ws, size_t ws_size,
                              hipStream_t stream) {
  const int*   configs = (const int*)  d_in[0];
  const float* tok     = (const float*)d_in[1];
  const float* pos     = (const float*)d_in[2];
  const float* W       = (const float*)d_in[3];
  const float* bv      = (const float*)d_in[4];

  float*  wsf  = (float*)d_ws;
  float*  T    = wsf;                       // 4*400 floats
  float*  P    = wsf + 4 * NTAB;            // 144*400 floats
  double* dets = (double*)(wsf + TP_FLOATS);  // 236800B offset, 8-aligned
  const int B = in_sizes[0] / NSITE;        // total ws: ~499KB

  tp_kernel<<<(148 * NTAB + 255) / 256, 256, 0, stream>>>(tok, pos, W, bv, T, P);
  dim3 grid(B, 2);
  det_kernel<<<grid, 256, 0, stream>>>(configs, T, P, dets);
  combine_kernel<<<(B + 255) / 256, 256, 0, stream>>>(dets, (float*)d_out, B);
}